// Round 22
// baseline (2684.643 us; speedup 1.0000x reference)
//
#include <hip/hip_runtime.h>
#include <hip/hip_bf16.h>
#include <cstdint>
#include <cstddef>

#define H 128

using f32x4v = __attribute__((ext_vector_type(4))) float;
using bf8 = __attribute__((ext_vector_type(8))) short;

__device__ __forceinline__ short f2bf(float f) {
  unsigned u = __float_as_uint(f);
  u = (u + 0x7fffu + ((u >> 16) & 1u)) >> 16;
  return (short)u;
}
__device__ __forceinline__ float bf2f(short h) {
  return __uint_as_float(((unsigned)(unsigned short)h) << 16);
}
__device__ __forceinline__ void splitf(float f, short& h, short& l) {
  h = f2bf(f);
  l = f2bf(f - bf2f(h));
}
__device__ __forceinline__ f32x4v mfma16(bf8 a, bf8 b, f32x4v c) {
  return __builtin_amdgcn_mfma_f32_16x16x32_bf16(a, b, c, 0, 0, 0);
}

// direct global->LDS 16B async copy (dest must be lane-linear within the wave)
__device__ __forceinline__ void stage16(const void* gsrc, void* ldst) {
  __builtin_amdgcn_global_load_lds(
      (const __attribute__((address_space(1))) void*)gsrc,
      (__attribute__((address_space(3))) void*)ldst, 16, 0, 0);
}

__device__ __forceinline__ void load_afrags(const float* __restrict__ Ap, bool av,
    float sc, bf8* ah, bf8* al_) {
#pragma unroll
  for (int ks = 0; ks < 4; ++ks) {
    float v[8];
    if (av) {
      f32x4v p0 = *(const f32x4v*)(Ap + ks * 32);
      f32x4v p1 = *(const f32x4v*)(Ap + ks * 32 + 4);
      v[0]=p0.x*sc; v[1]=p0.y*sc; v[2]=p0.z*sc; v[3]=p0.w*sc;
      v[4]=p1.x*sc; v[5]=p1.y*sc; v[6]=p1.z*sc; v[7]=p1.w*sc;
    } else {
#pragma unroll
      for (int j = 0; j < 8; ++j) v[j] = 0.f;
    }
#pragma unroll
    for (int j = 0; j < 8; ++j) { short hh, ll; splitf(v[j], hh, ll); ah[ks][j]=hh; al_[ks][j]=ll; }
  }
}

// ---------------- weight packing ----------------

__global__ __launch_bounds__(256) void pack_w_k(const float* __restrict__ W,
    short* __restrict__ hi, short* __restrict__ lo, int K, int N) {
  int total = K * N;
  int t = blockIdx.x * 256 + threadIdx.x;
  int layer = blockIdx.y;
  if (t >= total) return;
  int k = t / N, n = t - k * N;
  float f = W[(size_t)layer * total + t];
  short h, l; splitf(f, h, l);
  int nt = n >> 4, ks = k >> 5, kk = k & 31;
  int lane = (n & 15) | (((kk >> 3) & 3) << 4);
  size_t idx = (size_t)layer * total + ((size_t)(nt * (K >> 5) + ks) << 9) + lane * 8 + (kk & 7);
  hi[idx] = h; lo[idx] = l;
}

// ---------------- embedding / init ----------------

__global__ __launch_bounds__(256) void atom_encode_k(const int* __restrict__ nf,
    const float* __restrict__ emb, float* __restrict__ x, int N) {
  long long t = (long long)blockIdx.x * 256 + threadIdx.x;
  if (t >= (long long)N * H) return;
  int n = (int)(t >> 7), h = (int)(t & 127);
  const int* row = nf + (size_t)n * 9;
  float s = 0.f;
#pragma unroll
  for (int f = 0; f < 9; ++f) s += emb[((size_t)f * 100 + row[f]) * H + h];
  x[t] = s;
}

__global__ __launch_bounds__(256) void rg_init_k(const int* __restrict__ feat,
    const float* __restrict__ emb, float* __restrict__ rg, int NRG) {
  long long t = (long long)blockIdx.x * 256 + threadIdx.x;
  if (t >= (long long)NRG * H) return;
  int n = (int)(t >> 7), h = (int)(t & 127);
  rg[t] = emb[(size_t)feat[n] * H + h];
}

// ---------------- CSR build ----------------

__global__ __launch_bounds__(256) void icount_k(const int* __restrict__ idx,
    int* __restrict__ cnt, int n) {
  int t = blockIdx.x * 256 + threadIdx.x;
  if (t < n) atomicAdd(&cnt[idx[t]], 1);
}

__global__ __launch_bounds__(256) void inv_from_int_k(const int* __restrict__ c,
    float* __restrict__ inv, int n) {
  int t = blockIdx.x * 256 + threadIdx.x;
  if (t < n) inv[t] = 1.0f / (float)max(c[t], 1);
}

__global__ __launch_bounds__(256) void seg_blocksum_k(const int* __restrict__ cnt,
    int* __restrict__ bsum, int n) {
  __shared__ int red[256];
  int base = blockIdx.x * 1024;
  int s = 0;
  for (int i = threadIdx.x; i < 1024; i += 256) {
    int idx = base + i;
    s += (idx < n) ? cnt[idx] : 0;
  }
  red[threadIdx.x] = s; __syncthreads();
  for (int st = 128; st > 0; st >>= 1) {
    if (threadIdx.x < st) red[threadIdx.x] += red[threadIdx.x + st];
    __syncthreads();
  }
  if (threadIdx.x == 0) bsum[blockIdx.x] = red[0];
}

__global__ __launch_bounds__(256) void seg_scan_k(const int* __restrict__ cnt,
    const int* __restrict__ bsum, int* __restrict__ off, int* __restrict__ cur,
    int n, int nblk) {
  __shared__ int pref;
  __shared__ int tsum[257];
  int b = blockIdx.x;
  if (threadIdx.x == 0) {
    int p = 0;
    for (int j = 0; j < b; ++j) p += bsum[j];
    pref = p;
  }
  int base = b * 1024 + threadIdx.x * 4;
  int v[4]; int s = 0;
#pragma unroll
  for (int j = 0; j < 4; ++j) { int idx = base + j; v[j] = (idx < n) ? cnt[idx] : 0; s += v[j]; }
  tsum[threadIdx.x + 1] = s;
  if (threadIdx.x == 0) tsum[0] = 0;
  __syncthreads();
  if (threadIdx.x == 0) { for (int j = 1; j <= 256; ++j) tsum[j] += tsum[j - 1]; }
  __syncthreads();
  int run = pref + tsum[threadIdx.x];
#pragma unroll
  for (int j = 0; j < 4; ++j) {
    int idx = base + j;
    if (idx < n) { off[idx] = run; cur[idx] = run; }
    run += v[j];
  }
  if (b == 0 && threadIdx.x == 0) {
    int tot = 0;
    for (int j = 0; j < nblk; ++j) tot += bsum[j];
    off[n] = tot;
  }
}

__global__ __launch_bounds__(256) void seg_fill_k(const int* __restrict__ idx,
    int* __restrict__ cur, int* __restrict__ ids, int n) {
  int t = blockIdx.x * 256 + threadIdx.x;
  if (t < n) { int p = atomicAdd(&cur[idx[t]], 1); ids[p] = t; }
}

// ---------------- gather aggregations ----------------

__global__ __launch_bounds__(256) void gine_agg_k(const int* __restrict__ off,
    const int* __restrict__ ids, const int* __restrict__ ei, const int* __restrict__ ef,
    const float* __restrict__ bemb, const float* __restrict__ x,
    float* __restrict__ out, int N) {
  int n = blockIdx.x * 8 + (threadIdx.x >> 5);
  if (n >= N) return;
  int c4 = (threadIdx.x & 31) * 4;
  float4 acc = *(const float4*)(x + (size_t)n * H + c4);
  float4 acc2 = make_float4(0.f, 0.f, 0.f, 0.f);
  int p0 = off[n], p1 = off[n + 1];
  int p = p0;
  for (; p + 1 < p1; p += 2) {
    int e0 = ids[p], e1 = ids[p + 1];
    int s0 = ei[e0], s1 = ei[e1];
    const int* f0 = ef + (size_t)e0 * 3;
    const int* f1 = ef + (size_t)e1 * 3;
    float4 a0 = *(const float4*)(bemb + (size_t)f0[0] * H + c4);
    float4 a1 = *(const float4*)(bemb + ((size_t)100 + f0[1]) * H + c4);
    float4 a2 = *(const float4*)(bemb + ((size_t)200 + f0[2]) * H + c4);
    float4 xa = *(const float4*)(x + (size_t)s0 * H + c4);
    float4 b0 = *(const float4*)(bemb + (size_t)f1[0] * H + c4);
    float4 b1 = *(const float4*)(bemb + ((size_t)100 + f1[1]) * H + c4);
    float4 b2 = *(const float4*)(bemb + ((size_t)200 + f1[2]) * H + c4);
    float4 xb = *(const float4*)(x + (size_t)s1 * H + c4);
    acc.x += fmaxf(xa.x + a0.x + a1.x + a2.x, 0.f);
    acc.y += fmaxf(xa.y + a0.y + a1.y + a2.y, 0.f);
    acc.z += fmaxf(xa.z + a0.z + a1.z + a2.z, 0.f);
    acc.w += fmaxf(xa.w + a0.w + a1.w + a2.w, 0.f);
    acc2.x += fmaxf(xb.x + b0.x + b1.x + b2.x, 0.f);
    acc2.y += fmaxf(xb.y + b0.y + b1.y + b2.y, 0.f);
    acc2.z += fmaxf(xb.z + b0.z + b1.z + b2.z, 0.f);
    acc2.w += fmaxf(xb.w + b0.w + b1.w + b2.w, 0.f);
  }
  if (p < p1) {
    int e = ids[p];
    int src = ei[e];
    const int* f = ef + (size_t)e * 3;
    float4 v0 = *(const float4*)(bemb + (size_t)f[0] * H + c4);
    float4 v1 = *(const float4*)(bemb + ((size_t)100 + f[1]) * H + c4);
    float4 v2 = *(const float4*)(bemb + ((size_t)200 + f[2]) * H + c4);
    float4 xs = *(const float4*)(x + (size_t)src * H + c4);
    acc.x += fmaxf(xs.x + v0.x + v1.x + v2.x, 0.f);
    acc.y += fmaxf(xs.y + v0.y + v1.y + v2.y, 0.f);
    acc.z += fmaxf(xs.z + v0.z + v1.z + v2.z, 0.f);
    acc.w += fmaxf(xs.w + v0.w + v1.w + v2.w, 0.f);
  }
  acc.x += acc2.x; acc.y += acc2.y; acc.z += acc2.z; acc.w += acc2.w;
  *(float4*)(out + (size_t)n * H + c4) = acc;
}

__global__ __launch_bounds__(256) void gather_agg_k(const int* __restrict__ off,
    const int* __restrict__ ids, const int* __restrict__ sidx,
    const float* __restrict__ src, const float* __restrict__ base,
    float* __restrict__ out, int N) {
  int n = blockIdx.x * 8 + (threadIdx.x >> 5);
  if (n >= N) return;
  int c4 = (threadIdx.x & 31) * 4;
  float4 acc = make_float4(0.f, 0.f, 0.f, 0.f);
  float4 acc2 = make_float4(0.f, 0.f, 0.f, 0.f);
  if (base) acc = *(const float4*)(base + (size_t)n * H + c4);
  int p0 = off[n], p1 = off[n + 1];
  int p = p0;
  for (; p + 1 < p1; p += 2) {
    int m0 = ids[p], m1 = ids[p + 1];
    int s0 = sidx ? sidx[m0] : m0;
    int s1 = sidx ? sidx[m1] : m1;
    float4 v0 = *(const float4*)(src + (size_t)s0 * H + c4);
    float4 v1 = *(const float4*)(src + (size_t)s1 * H + c4);
    acc.x += v0.x; acc.y += v0.y; acc.z += v0.z; acc.w += v0.w;
    acc2.x += v1.x; acc2.y += v1.y; acc2.z += v1.z; acc2.w += v1.w;
  }
  if (p < p1) {
    int m = ids[p];
    int sr = sidx ? sidx[m] : m;
    float4 v = *(const float4*)(src + (size_t)sr * H + c4);
    acc.x += v.x; acc.y += v.y; acc.z += v.z; acc.w += v.w;
  }
  acc.x += acc2.x; acc.y += acc2.y; acc.z += acc2.z; acc.w += acc2.w;
  *(float4*)(out + (size_t)n * H + c4) = acc;
}

__device__ __forceinline__ int lowb(const int* __restrict__ a, int n, int v) {
  int lo = 0, hi = n;
  while (lo < hi) { int mid = (lo + hi) >> 1; if (a[mid] < v) lo = mid + 1; else hi = mid; }
  return lo;
}

__global__ __launch_bounds__(256) void pool_mean_k(const int* __restrict__ bidx,
    const float* __restrict__ src, float* __restrict__ out, int n, int G) {
  int g = blockIdx.x * 8 + (threadIdx.x >> 5);
  if (g >= G) return;
  int c4 = (threadIdx.x & 31) * 4;
  int lo = lowb(bidx, n, g), hi = lowb(bidx, n, g + 1);
  float4 acc = make_float4(0.f, 0.f, 0.f, 0.f);
  for (int r = lo; r < hi; ++r) {
    float4 v = *(const float4*)(src + (size_t)r * H + c4);
    acc.x += v.x; acc.y += v.y; acc.z += v.z; acc.w += v.w;
  }
  float inv = 1.0f / (float)max(hi - lo, 1);
  acc.x *= inv; acc.y *= inv; acc.z *= inv; acc.w *= inv;
  *(float4*)(out + (size_t)g * H + c4) = acc;
}

// ---------------- batchnorm helpers ----------------

__global__ void bn_final_k(float* __restrict__ ssum, float* __restrict__ ssq,
    float* __restrict__ mu, float* __restrict__ rsig, int C, float invM) {
  int c = threadIdx.x;
  if (c < C) {
    float m = ssum[c] * invM;
    float v = ssq[c] * invM - m * m;
    mu[c] = m;
    rsig[c] = rsqrtf(v + 1e-5f);
  }
  ssum[c] = 0.f;
  ssq[c] = 0.f;
}

__global__ __launch_bounds__(256) void bn_apply_relu_k(const float* __restrict__ X,
    const float* __restrict__ mu, const float* __restrict__ rsig,
    float* __restrict__ Out, int M) {
  long long t = (long long)blockIdx.x * 256 + threadIdx.x;
  if (t >= (long long)M * 32) return;
  int c4 = ((int)(t & 31)) * 4;
  float4 v = ((const float4*)X)[t];
  float4 m4 = *(const float4*)&mu[c4];
  float4 r4 = *(const float4*)&rsig[c4];
  v.x = fmaxf((v.x - m4.x) * r4.x, 0.f);
  v.y = fmaxf((v.y - m4.y) * r4.y, 0.f);
  v.z = fmaxf((v.z - m4.z) * r4.z, 0.f);
  v.w = fmaxf((v.w - m4.w) * r4.w, 0.f);
  ((float4*)Out)[t] = v;
}

// ---------------- MFMA MLP stats: pair-tiled, double-buffered W prefetch ----------------

__global__ __launch_bounds__(512) void mlp_stats_mfma_k(
    const float* __restrict__ A, const short* __restrict__ w1h, const short* __restrict__ w1l,
    float* __restrict__ ssum, float* __restrict__ ssq, int M, int npairs) {
  __shared__ __align__(16) short Wch[2][8192], Wcl[2][8192];  // 64 KB
  __shared__ float sRed[256], qRed[256];
  int tid = threadIdx.x;
  if (tid < 256) { sRed[tid] = 0.f; qRed[tid] = 0.f; }
  int w = tid >> 6, l = tid & 63, l15 = l & 15, lg = l >> 4;
  int h = w >> 2, wl = w & 3;
  float sAcc[16], qAcc[16];
#pragma unroll
  for (int nt = 0; nt < 16; ++nt) { sAcc[nt] = 0.f; qAcc[nt] = 0.f; }
  for (int pb = blockIdx.x; pb < npairs; pb += gridDim.x) {
    int tile = pb * 2 + h;
    int arow = tile * 64 + wl * 16 + l15;
    bool av = arow < M;
    bf8 ah[4], al_[4];
    load_afrags(A + (size_t)arow * 128 + lg * 8, av, 1.f, ah, al_);
    auto stageW1 = [&](int ch, int buf) {
      const bf8* srcH = (const bf8*)(w1h + ch * 8192);
      const bf8* srcL = (const bf8*)(w1l + ch * 8192);
      for (int it = tid; it < 1024; it += 512) {
        stage16(srcH + it, ((bf8*)Wch[buf]) + it);
        stage16(srcL + it, ((bf8*)Wcl[buf]) + it);
      }
    };
    __syncthreads();            // prior tile's buffer reads complete
    stageW1(0, 0);
    for (int ch = 0; ch < 4; ++ch) {
      __syncthreads();
      if (ch < 3) stageW1(ch + 1, (ch + 1) & 1);
#pragma unroll
      for (int ntl = 0; ntl < 4; ++ntl) {
        f32x4v c = {0.f, 0.f, 0.f, 0.f};
#pragma unroll
        for (int ks = 0; ks < 4; ++ks) {
          bf8 bh = *(const bf8*)&Wch[ch & 1][(ntl * 4 + ks) * 512 + l * 8];
          bf8 bl = *(const bf8*)&Wcl[ch & 1][(ntl * 4 + ks) * 512 + l * 8];
          c = mfma16(al_[ks], bh, c);
          c = mfma16(ah[ks], bl, c);
          c = mfma16(ah[ks], bh, c);
        }
        int nt = ch * 4 + ntl;
        if (av) {
          sAcc[nt] += c[0] + c[1] + c[2] + c[3];
          qAcc[nt] += c[0]*c[0] + c[1]*c[1] + c[2]*c[2] + c[3]*c[3];
        }
      }
    }
  }
  __syncthreads();
#pragma unroll
  for (int nt = 0; nt < 16; ++nt) {
    float s = sAcc[nt], q = qAcc[nt];
    s += __shfl_xor(s, 16); s += __shfl_xor(s, 32);
    q += __shfl_xor(q, 16); q += __shfl_xor(q, 32);
    if (l < 16) { atomicAdd(&sRed[nt * 16 + l], s); atomicAdd(&qRed[nt * 16 + l], q); }
  }
  __syncthreads();
  if (tid < 256) { atomicAdd(&ssum[tid], sRed[tid]); atomicAdd(&ssq[tid], qRed[tid]); }
}

// ---------------- MFMA fused MLP: pair-tiled, double-buffered W prefetch ----------------
// 8 phases/tile: barrier; stage(chunk c+1 -> other buf); MFMA(chunk c).
// h1f is wave-local (same-wave rows for write and a2-read) -> no barrier needed for it.

__global__ __launch_bounds__(512) void mlp_fused_mfma_k(
    float* __restrict__ A, const short* __restrict__ w1h, const short* __restrict__ w1l,
    const short* __restrict__ w2h, const short* __restrict__ w2l,
    const float* __restrict__ mu, const float* __restrict__ rsig,
    float* __restrict__ ssum, float* __restrict__ ssq, int M, int npairs) {
  __shared__ __align__(16) short Wch[2][8192], Wcl[2][8192];  // 64 KB
  __shared__ __align__(16) float h1f[2][64][132];             // 67.6 KB
  __shared__ float sRed[128], qRed[128];
  int tid = threadIdx.x;
  if (tid < 128) { sRed[tid] = 0.f; qRed[tid] = 0.f; }
  int w = tid >> 6, l = tid & 63, l15 = l & 15, lg = l >> 4;
  int h = w >> 2, wl = w & 3;
  float sAcc[8], qAcc[8];
#pragma unroll
  for (int nt = 0; nt < 8; ++nt) { sAcc[nt] = 0.f; qAcc[nt] = 0.f; }
  for (int pb = blockIdx.x; pb < npairs; pb += gridDim.x) {
    int tile = pb * 2 + h;
    int arow = tile * 64 + wl * 16 + l15;
    bool av = arow < M;
    f32x4v acc[8];
#pragma unroll
    for (int nt = 0; nt < 8; ++nt) acc[nt] = (f32x4v){0.f, 0.f, 0.f, 0.f};
    bf8 ah[4], al_[4];
    load_afrags(A + (size_t)arow * 128 + lg * 8, av, 1.f, ah, al_);
    bf8 a2h[4], a2l[4];

    auto stageW1 = [&](int cbase, int buf) {
      const bf8* srcH = (const bf8*)(w1h + cbase * 2048);
      const bf8* srcL = (const bf8*)(w1l + cbase * 2048);
      for (int it = tid; it < 1024; it += 512) {
        stage16(srcH + it, ((bf8*)Wch[buf]) + it);
        stage16(srcL + it, ((bf8*)Wcl[buf]) + it);
      }
    };
    auto stageW2 = [&](int kh, int c2, int buf) {
      for (int it = tid; it < 1024; it += 512) {
        int e = it * 8;
        int ntl = e >> 11, rem = e & 2047;
        int ks2 = rem >> 9, s = rem & 511;
        int src = ((c2 * 4 + ntl) * 8 + kh * 4 + ks2) * 512 + s;
        stage16((const bf8*)(w2h + src), ((bf8*)Wch[buf]) + it);
        stage16((const bf8*)(w2l + src), ((bf8*)Wcl[buf]) + it);
      }
    };
    auto mfmaW1 = [&](int cbase, int buf) {
#pragma unroll
      for (int ntl = 0; ntl < 4; ++ntl) {
        f32x4v c = {0.f, 0.f, 0.f, 0.f};
#pragma unroll
        for (int ks = 0; ks < 4; ++ks) {
          bf8 bh = *(const bf8*)&Wch[buf][(ntl * 4 + ks) * 512 + l * 8];
          bf8 bl = *(const bf8*)&Wcl[buf][(ntl * 4 + ks) * 512 + l * 8];
          c = mfma16(al_[ks], bh, c);
          c = mfma16(ah[ks], bl, c);
          c = mfma16(ah[ks], bh, c);
        }
        int cn = cbase + ntl;
        int cc = cn * 16 + l15;
        float mm = mu[cc], rs = rsig[cc];
#pragma unroll
        for (int r = 0; r < 4; ++r) {
          float t = fmaxf((c[r] - mm) * rs, 0.f);
          h1f[h][wl * 16 + lg * 4 + r][(cn & 7) * 16 + l15] = t;
        }
      }
    };
    auto buildA2 = [&]() {
#pragma unroll
      for (int ks2 = 0; ks2 < 4; ++ks2) {
        const float* hp = &h1f[h][wl * 16 + l15][ks2 * 32 + lg * 8];
#pragma unroll
        for (int j = 0; j < 8; ++j) {
          short hh, ll; splitf(hp[j], hh, ll);
          a2h[ks2][j] = hh; a2l[ks2][j] = ll;
        }
      }
    };
    auto mfmaW2 = [&](int c2, int buf) {
#pragma unroll
      for (int ntl = 0; ntl < 4; ++ntl) {
        f32x4v c = acc[c2 * 4 + ntl];
#pragma unroll
        for (int ks2 = 0; ks2 < 4; ++ks2) {
          bf8 bh = *(const bf8*)&Wch[buf][(ntl * 4 + ks2) * 512 + l * 8];
          bf8 bl = *(const bf8*)&Wcl[buf][(ntl * 4 + ks2) * 512 + l * 8];
          c = mfma16(a2l[ks2], bh, c);
          c = mfma16(a2h[ks2], bl, c);
          c = mfma16(a2h[ks2], bh, c);
        }
        acc[c2 * 4 + ntl] = c;
      }
    };

    __syncthreads();            // prior tile's buffer reads complete
    stageW1(0, 0);              // chunk 0 (exposed once per tile)
    // P0
    __syncthreads();
    stageW1(4, 1);
    mfmaW1(0, 0);
    // P1
    __syncthreads();
    stageW2(0, 0, 0);
    mfmaW1(4, 1);
    buildA2();                  // kh0 a2 frags (wave-local h1f)
    // P2
    __syncthreads();
    stageW2(0, 1, 1);
    mfmaW2(0, 0);
    // P3
    __syncthreads();
    stageW1(8, 0);
    mfmaW2(1, 1);
    // P4
    __syncthreads();
    stageW1(12, 1);
    mfmaW1(8, 0);
    // P5
    __syncthreads();
    stageW2(1, 0, 0);
    mfmaW1(12, 1);
    buildA2();                  // kh1 a2 frags
    // P6
    __syncthreads();
    stageW2(1, 1, 1);
    mfmaW2(0, 0);
    // P7
    __syncthreads();
    mfmaW2(1, 1);

    int base = tile * 64 + wl * 16;
#pragma unroll
    for (int nt = 0; nt < 8; ++nt) {
      int cc = nt * 16 + l15;
#pragma unroll
      for (int r = 0; r < 4; ++r) {
        int gr = base + lg * 4 + r;
        if (gr < M) {
          float vv = acc[nt][r];
          A[(size_t)gr * 128 + cc] = vv;
          sAcc[nt] += vv;
          qAcc[nt] = fmaf(vv, vv, qAcc[nt]);
        }
      }
    }
  }
  __syncthreads();
#pragma unroll
  for (int nt = 0; nt < 8; ++nt) {
    float s = sAcc[nt], q = qAcc[nt];
    s += __shfl_xor(s, 16); s += __shfl_xor(s, 32);
    q += __shfl_xor(q, 16); q += __shfl_xor(q, 32);
    if (l < 16) { atomicAdd(&sRed[nt * 16 + l], s); atomicAdd(&qRed[nt * 16 + l], q); }
  }
  __syncthreads();
  if (tid < 128) { atomicAdd(&ssum[tid], sRed[tid]); atomicAdd(&ssq[tid], qRed[tid]); }
}

// ---------------- MFMA 128x128 GEMM: Out = Out + relu((A*aux) @ W) ----------------
// hi-plane staged in LDS (32 KB); lo-plane read directly from L2-resident global.

__global__ __launch_bounds__(256) void gemm128_mfma_k(
    const float* __restrict__ A0, const float* __restrict__ AUX,
    const short* __restrict__ wh, const short* __restrict__ wl,
    float* __restrict__ Out, int M, int ntiles) {
  __shared__ __align__(16) short Wh[16384];
  int tid = threadIdx.x;
  for (int i = tid; i < 2048; i += 256) {
    stage16((const f32x4v*)wh + i, ((f32x4v*)Wh) + i);
  }
  __syncthreads();
  int w = tid >> 6, l = tid & 63, l15 = l & 15, lg = l >> 4;
  const bf8* wlp = (const bf8*)wl;
  for (int tb = blockIdx.x; tb < ntiles; tb += gridDim.x) {
    int arow = tb * 64 + w * 16 + l15;
    bool av = arow < M;
    float sc = av ? AUX[arow] : 0.f;
    bf8 ah[4], al_[4];
    load_afrags(A0 + (size_t)arow * 128 + lg * 8, av, sc, ah, al_);
    int base = tb * 64 + w * 16;
#pragma unroll 2
    for (int nt = 0; nt < 8; ++nt) {
      f32x4v c = {0.f, 0.f, 0.f, 0.f};
#pragma unroll
      for (int ks = 0; ks < 4; ++ks) {
        bf8 bh = *(const bf8*)&Wh[(nt * 4 + ks) * 512 + l * 8];
        bf8 bl = wlp[(nt * 4 + ks) * 64 + l];
        c = mfma16(al_[ks], bh, c);
        c = mfma16(ah[ks], bl, c);
        c = mfma16(ah[ks], bh, c);
      }
#pragma unroll
      for (int r = 0; r < 4; ++r) {
        int gr = base + lg * 4 + r;
        if (gr < M) {
          size_t o = (size_t)gr * 128 + nt * 16 + l15;
          Out[o] = Out[o] + fmaxf(c[r], 0.f);
        }
      }
    }
  }
}

// ---------------- f32 GEMM for readout ----------------
template<int EPI>
__global__ __launch_bounds__(256) void gemm_k(
    const float* __restrict__ A0, const float* __restrict__ W,
    float* __restrict__ Out, int M) {
  __shared__ __align__(16) float Ash[64][64];
  int tid = threadIdx.x;
  int tc = tid & 63, tr = tid >> 6;
  int row0 = blockIdx.x * 64;
  float acc[16][2];
#pragma unroll
  for (int i = 0; i < 16; ++i) { acc[i][0] = 0.f; acc[i][1] = 0.f; }
  for (int k0 = 0; k0 < 128; k0 += 64) {
#pragma unroll
    for (int it = 0; it < 4; ++it) {
      int fidx = tid + it * 256;
      int r = fidx >> 4, c4 = (fidx & 15) << 2;
      int gr = row0 + r;
      float4 v = make_float4(0.f, 0.f, 0.f, 0.f);
      if (gr < M) v = *(const float4*)(A0 + (size_t)gr * 128 + k0 + c4);
      *(float4*)&Ash[r][c4] = v;
    }
    __syncthreads();
    const float* Wp = W + (size_t)k0 * 128 + tc;
    for (int kk = 0; kk < 64; kk += 4) {
      float w[4][2];
#pragma unroll
      for (int kj = 0; kj < 4; ++kj)
#pragma unroll
        for (int j = 0; j < 2; ++j) w[kj][j] = Wp[(size_t)(kk + kj) * 128 + j * 64];
#pragma unroll
      for (int i = 0; i < 16; ++i) {
        float4 a = *(const float4*)&Ash[tr * 16 + i][kk];
#pragma unroll
        for (int j = 0; j < 2; ++j) {
          acc[i][j] = fmaf(a.x, w[0][j], acc[i][j]);
          acc[i][j] = fmaf(a.y, w[1][j], acc[i][j]);
          acc[i][j] = fmaf(a.z, w[2][j], acc[i][j]);
          acc[i][j] = fmaf(a.w, w[3][j], acc[i][j]);
        }
      }
    }
    __syncthreads();
  }
#pragma unroll
  for (int i = 0; i < 16; ++i) {
    int gr = row0 + tr * 16 + i;
    if (gr < M) {
#pragma unroll
      for (int j = 0; j < 2; ++j) {
        size_t o = (size_t)gr * 128 + tc + j * 64;
        float v = acc[i][j];
        if (EPI == 0) Out[o] = v;
        else Out[o] = fmaxf(Out[o] + v, 0.f);
      }
    }
  }
}

// ---------------- host ----------------

static inline int cdivll(long long a, long long b) { return (int)((a + b - 1) / b); }

extern "C" void kernel_launch(void* const* d_in, const int* in_sizes, int n_in,
                              void* d_out, int out_size, void* d_ws, size_t ws_size,
                              hipStream_t stream) {
  const int* node_feat  = (const int*)d_in[0];
  const int* edge_index = (const int*)d_in[1];
  const int* edge_feat  = (const int*)d_in[2];
  const int* batch      = (const int*)d_in[3];
  const int* map_row    = (const int*)d_in[4];
  const int* map_col    = (const int*)d_in[5];
  const int* rg_ei      = (const int*)d_in[6];
  const int* rg_feat    = (const int*)d_in[7];
  const int* tree_batch = (const int*)d_in[8];
  const float* atom_emb   = (const float*)d_in[10];
  const float* bond_emb   = (const float*)d_in[11];
  const float* rg_emb     = (const float*)d_in[12];
  const float* atom_W1    = (const float*)d_in[13];
  const float* atom_W2    = (const float*)d_in[14];
  const float* rg_W1      = (const float*)d_in[15];
  const float* rg_W2      = (const float*)d_in[16];
  const float* raw2rg_W   = (const float*)d_in[17];
  const float* rg2raw_W   = (const float*)d_in[18];
  const float* atom_lin_W = (const float*)d_in[19];
  const float* rg_lin_W   = (const float*)d_in[20];
  const float* lin_W      = (const float*)d_in[21];

  const int N   = in_sizes[0] / 9;
  const int E   = in_sizes[1] / 2;
  const int M   = in_sizes[4];
  const int NRG = in_sizes[7];
  const int ERG = in_sizes[6] / 2;
  const int G   = out_size / H;
  if (N <= 0 || G <= 0) return;

  const size_t NH = (size_t)N * H, RH = (size_t)NRG * H, GH = (size_t)G * H;
  const int cmax = max(N, NRG);

  const size_t nfloat = 2 * NH + RH + (size_t)NRG + (size_t)N + 2048;
  const size_t nint = (size_t)(N + 1) * 2 + (size_t)(NRG + 1) * 2
                    + (size_t)E + 2 * (size_t)M + (size_t)ERG + (size_t)cmax + 1024;
  const size_t nshort = 3 * (4 * 32768 + 2 * 16384);
  const size_t need = nfloat * 4 + nint * 4 + nshort * 2 + 256;
  if (ws_size < need) return;

  float* ws = (float*)d_ws;
  size_t off = 0;
  auto alloc = [&](size_t n) { float* p = ws + off; off += n; return p; };
  float* x       = alloc(NH);
  float* abuf    = alloc(NH);
  float* rg      = alloc(RH);
  float* inv_col = alloc((size_t)NRG);
  float* inv_row = alloc((size_t)N);
  float* ssum = alloc(256);
  float* ssq  = alloc(256);
  float* mu   = alloc(256);
  float* rsig = alloc(256);

  int* ip = (int*)(ws + off);
  size_t ioff = 0;
  auto ialloc = [&](size_t n) { int* p = ip + ioff; ioff += n; return p; };
  int* off_dst = ialloc((size_t)N + 1);
  int* off_col = ialloc((size_t)NRG + 1);
  int* off_row = ialloc((size_t)N + 1);
  int* off_rg  = ialloc((size_t)NRG + 1);
  int* ids_dst = ialloc((size_t)E);
  int* ids_col = ialloc((size_t)M);
  int* ids_row = ialloc((size_t)M);
  int* ids_rg  = ialloc((size_t)ERG);
  int* tmp_cnt = ialloc((size_t)cmax);
  int* bsum    = ialloc(1024);

  short* sp = (short*)(ip + ioff);
  size_t soff = 0;
  auto salloc = [&](size_t n) { short* p = sp + soff; soff += n; return p; };
  short* paW1h = salloc(3 * 32768); short* paW1l = salloc(3 * 32768);
  short* paW2h = salloc(3 * 32768); short* paW2l = salloc(3 * 32768);
  short* prW1h = salloc(3 * 32768); short* prW1l = salloc(3 * 32768);
  short* prW2h = salloc(3 * 32768); short* prW2l = salloc(3 * 32768);
  short* p2gh  = salloc(3 * 16384); short* p2gl  = salloc(3 * 16384);
  short* pg2h  = salloc(3 * 16384); short* pg2l  = salloc(3 * 16384);

  const int ta = (N + 63) >> 6, trg = (NRG + 63) >> 6;
  const int pa = (ta + 1) >> 1, prg = (trg + 1) >> 1;
  const int ga2 = pa < 512 ? pa : 512, grg2 = prg < 512 ? prg : 512;
  const int ga = ta < 1024 ? ta : 1024, grg = trg < 1024 ? trg : 1024;

  // ---- pack weights ----
  pack_w_k<<<dim3(128, 3), 256, 0, stream>>>(atom_W1, paW1h, paW1l, 128, 256);
  pack_w_k<<<dim3(128, 3), 256, 0, stream>>>(atom_W2, paW2h, paW2l, 256, 128);
  pack_w_k<<<dim3(128, 3), 256, 0, stream>>>(rg_W1, prW1h, prW1l, 128, 256);
  pack_w_k<<<dim3(128, 3), 256, 0, stream>>>(rg_W2, prW2h, prW2l, 256, 128);
  pack_w_k<<<dim3(64, 3), 256, 0, stream>>>(raw2rg_W, p2gh, p2gl, 128, 128);
  pack_w_k<<<dim3(64, 3), 256, 0, stream>>>(rg2raw_W, pg2h, pg2l, 128, 128);

  // ---- CSR builds ----
  auto build_csr = [&](const int* idx, int nelem, int nrows, int* offs, int* ids,
                       float* inv) {
    hipMemsetAsync(tmp_cnt, 0, (size_t)nrows * 4, stream);
    icount_k<<<cdivll(nelem, 256), 256, 0, stream>>>(idx, tmp_cnt, nelem);
    if (inv) inv_from_int_k<<<cdivll(nrows, 256), 256, 0, stream>>>(tmp_cnt, inv, nrows);
    int nblk = cdivll(nrows, 1024);
    seg_blocksum_k<<<nblk, 256, 0, stream>>>(tmp_cnt, bsum, nrows);
    seg_scan_k<<<nblk, 256, 0, stream>>>(tmp_cnt, bsum, offs, tmp_cnt, nrows, nblk);
    seg_fill_k<<<cdivll(nelem, 256), 256, 0, stream>>>(idx, tmp_cnt, ids, nelem);
  };
  build_csr(edge_index + E, E, N, off_dst, ids_dst, nullptr);
  build_csr(map_col, M, NRG, off_col, ids_col, inv_col);
  build_csr(map_row, M, N, off_row, ids_row, inv_row);
  build_csr(rg_ei + ERG, ERG, NRG, off_rg, ids_rg, nullptr);

  // ---- encoders; initial stats zero ----
  hipMemsetAsync(ssum, 0, 512 * 4, stream);
  atom_encode_k<<<cdivll(NH, 256), 256, 0, stream>>>(node_feat, atom_emb, x, N);
  rg_init_k<<<cdivll(RH, 256), 256, 0, stream>>>(rg_feat, rg_emb, rg, NRG);

  for (int i = 0; i < 3; ++i) {
    // --- GINE: abuf = x + sum relu(x[src]+e) ---
    gine_agg_k<<<cdivll(N, 8), 256, 0, stream>>>(off_dst, ids_dst, edge_index, edge_feat,
        bond_emb + (size_t)i * 3 * 100 * H, x, abuf, N);
    // --- atom MLP ---
    mlp_stats_mfma_k<<<ga2, 512, 0, stream>>>(abuf, paW1h + i * 32768, paW1l + i * 32768, ssum, ssq, N, pa);
    bn_final_k<<<1, 256, 0, stream>>>(ssum, ssq, mu, rsig, 256, 1.0f / N);
    mlp_fused_mfma_k<<<ga2, 512, 0, stream>>>(abuf, paW1h + i * 32768, paW1l + i * 32768,
        paW2h + i * 32768, paW2l + i * 32768, mu, rsig, ssum, ssq, N, pa);
    bn_final_k<<<1, 256, 0, stream>>>(ssum, ssq, mu, rsig, 128, 1.0f / N);
    bn_apply_relu_k<<<cdivll((long long)N * 32, 256), 256, 0, stream>>>(abuf, mu, rsig, x, N);

    // --- raw -> rg ---
    gather_agg_k<<<cdivll(NRG, 8), 256, 0, stream>>>(off_col, ids_col, map_row, x, nullptr, abuf, NRG);
    gemm128_mfma_k<<<grg, 256, 0, stream>>>(abuf, inv_col, p2gh + i * 16384, p2gl + i * 16384,
        rg, NRG, trg);

    // --- rg GIN ---
    gather_agg_k<<<cdivll(NRG, 8), 256, 0, stream>>>(off_rg, ids_rg, rg_ei, rg, rg, abuf, NRG);
    mlp_stats_mfma_k<<<grg2, 512, 0, stream>>>(abuf, prW1h + i * 32768, prW1l + i * 32768, ssum, ssq, NRG, prg);
    bn_final_k<<<1, 256, 0, stream>>>(ssum, ssq, mu, rsig, 256, 1.0f / NRG);
    mlp_fused_mfma_k<<<grg2, 512, 0, stream>>>(abuf, prW1h + i * 32768, prW1l + i * 32768,
        prW2h + i * 32768, prW2l + i * 32768, mu, rsig, ssum, ssq, NRG, prg);
    bn_final_k<<<1, 256, 0, stream>>>(ssum, ssq, mu, rsig, 128, 1.0f / NRG);
    bn_apply_relu_k<<<cdivll((long long)NRG * 32, 256), 256, 0, stream>>>(abuf, mu, rsig, rg, NRG);

    // --- rg -> raw ---
    gather_agg_k<<<cdivll(N, 8), 256, 0, stream>>>(off_row, ids_row, map_col, rg, nullptr, abuf, N);
    gemm128_mfma_k<<<ga, 256, 0, stream>>>(abuf, inv_row, pg2h + i * 16384, pg2l + i * 16384,
        x, N, ta);
  }

  // ---- readout ----
  float* xg  = abuf;
  float* rgg = abuf + GH;
  float* P   = abuf + 2 * GH;
  pool_mean_k<<<cdivll(G, 8), 256, 0, stream>>>(batch, x, xg, N, G);
  pool_mean_k<<<cdivll(G, 8), 256, 0, stream>>>(tree_batch, rg, rgg, NRG, G);
  gemm_k<0><<<cdivll(G, 64), 256, 0, stream>>>(xg, atom_lin_W, P, G);
  gemm_k<2><<<cdivll(G, 64), 256, 0, stream>>>(rgg, rg_lin_W, P, G);
  gemm_k<0><<<cdivll(G, 64), 256, 0, stream>>>(P, lin_W, (float*)d_out, G);
}

// Round 23
// 2584.163 us; speedup vs baseline: 1.0389x; 1.0389x over previous
//
#include <hip/hip_runtime.h>
#include <hip/hip_bf16.h>
#include <cstdint>
#include <cstddef>

#define H 128

using f32x4v = __attribute__((ext_vector_type(4))) float;
using bf8 = __attribute__((ext_vector_type(8))) short;

__device__ __forceinline__ short f2bf(float f) {
  unsigned u = __float_as_uint(f);
  u = (u + 0x7fffu + ((u >> 16) & 1u)) >> 16;
  return (short)u;
}
__device__ __forceinline__ float bf2f(short h) {
  return __uint_as_float(((unsigned)(unsigned short)h) << 16);
}
__device__ __forceinline__ void splitf(float f, short& h, short& l) {
  h = f2bf(f);
  l = f2bf(f - bf2f(h));
}
__device__ __forceinline__ f32x4v mfma16(bf8 a, bf8 b, f32x4v c) {
  return __builtin_amdgcn_mfma_f32_16x16x32_bf16(a, b, c, 0, 0, 0);
}

// direct global->LDS 16B async copy (dest must be lane-linear within the wave)
__device__ __forceinline__ void stage16(const void* gsrc, void* ldst) {
  __builtin_amdgcn_global_load_lds(
      (const __attribute__((address_space(1))) void*)gsrc,
      (__attribute__((address_space(3))) void*)ldst, 16, 0, 0);
}

__device__ __forceinline__ void load_afrags(const float* __restrict__ Ap, bool av,
    float sc, bf8* ah, bf8* al_) {
#pragma unroll
  for (int ks = 0; ks < 4; ++ks) {
    float v[8];
    if (av) {
      f32x4v p0 = *(const f32x4v*)(Ap + ks * 32);
      f32x4v p1 = *(const f32x4v*)(Ap + ks * 32 + 4);
      v[0]=p0.x*sc; v[1]=p0.y*sc; v[2]=p0.z*sc; v[3]=p0.w*sc;
      v[4]=p1.x*sc; v[5]=p1.y*sc; v[6]=p1.z*sc; v[7]=p1.w*sc;
    } else {
#pragma unroll
      for (int j = 0; j < 8; ++j) v[j] = 0.f;
    }
#pragma unroll
    for (int j = 0; j < 8; ++j) { short hh, ll; splitf(v[j], hh, ll); ah[ks][j]=hh; al_[ks][j]=ll; }
  }
}

// ---------------- weight packing ----------------

__global__ __launch_bounds__(256) void pack_w_k(const float* __restrict__ W,
    short* __restrict__ hi, short* __restrict__ lo, int K, int N) {
  int total = K * N;
  int t = blockIdx.x * 256 + threadIdx.x;
  int layer = blockIdx.y;
  if (t >= total) return;
  int k = t / N, n = t - k * N;
  float f = W[(size_t)layer * total + t];
  short h, l; splitf(f, h, l);
  int nt = n >> 4, ks = k >> 5, kk = k & 31;
  int lane = (n & 15) | (((kk >> 3) & 3) << 4);
  size_t idx = (size_t)layer * total + ((size_t)(nt * (K >> 5) + ks) << 9) + lane * 8 + (kk & 7);
  hi[idx] = h; lo[idx] = l;
}

// ---------------- embedding / init ----------------

__global__ __launch_bounds__(256) void atom_encode_k(const int* __restrict__ nf,
    const float* __restrict__ emb, float* __restrict__ x, int N) {
  long long t = (long long)blockIdx.x * 256 + threadIdx.x;
  if (t >= (long long)N * H) return;
  int n = (int)(t >> 7), h = (int)(t & 127);
  const int* row = nf + (size_t)n * 9;
  float s = 0.f;
#pragma unroll
  for (int f = 0; f < 9; ++f) s += emb[((size_t)f * 100 + row[f]) * H + h];
  x[t] = s;
}

__global__ __launch_bounds__(256) void rg_init_k(const int* __restrict__ feat,
    const float* __restrict__ emb, float* __restrict__ rg, int NRG) {
  long long t = (long long)blockIdx.x * 256 + threadIdx.x;
  if (t >= (long long)NRG * H) return;
  int n = (int)(t >> 7), h = (int)(t & 127);
  rg[t] = emb[(size_t)feat[n] * H + h];
}

// ---------------- CSR build ----------------

__global__ __launch_bounds__(256) void icount_k(const int* __restrict__ idx,
    int* __restrict__ cnt, int n) {
  int t = blockIdx.x * 256 + threadIdx.x;
  if (t < n) atomicAdd(&cnt[idx[t]], 1);
}

__global__ __launch_bounds__(256) void inv_from_int_k(const int* __restrict__ c,
    float* __restrict__ inv, int n) {
  int t = blockIdx.x * 256 + threadIdx.x;
  if (t < n) inv[t] = 1.0f / (float)max(c[t], 1);
}

__global__ __launch_bounds__(256) void seg_blocksum_k(const int* __restrict__ cnt,
    int* __restrict__ bsum, int n) {
  __shared__ int red[256];
  int base = blockIdx.x * 1024;
  int s = 0;
  for (int i = threadIdx.x; i < 1024; i += 256) {
    int idx = base + i;
    s += (idx < n) ? cnt[idx] : 0;
  }
  red[threadIdx.x] = s; __syncthreads();
  for (int st = 128; st > 0; st >>= 1) {
    if (threadIdx.x < st) red[threadIdx.x] += red[threadIdx.x + st];
    __syncthreads();
  }
  if (threadIdx.x == 0) bsum[blockIdx.x] = red[0];
}

__global__ __launch_bounds__(256) void seg_scan_k(const int* __restrict__ cnt,
    const int* __restrict__ bsum, int* __restrict__ off, int* __restrict__ cur,
    int n, int nblk) {
  __shared__ int pref;
  __shared__ int tsum[257];
  int b = blockIdx.x;
  if (threadIdx.x == 0) {
    int p = 0;
    for (int j = 0; j < b; ++j) p += bsum[j];
    pref = p;
  }
  int base = b * 1024 + threadIdx.x * 4;
  int v[4]; int s = 0;
#pragma unroll
  for (int j = 0; j < 4; ++j) { int idx = base + j; v[j] = (idx < n) ? cnt[idx] : 0; s += v[j]; }
  tsum[threadIdx.x + 1] = s;
  if (threadIdx.x == 0) tsum[0] = 0;
  __syncthreads();
  if (threadIdx.x == 0) { for (int j = 1; j <= 256; ++j) tsum[j] += tsum[j - 1]; }
  __syncthreads();
  int run = pref + tsum[threadIdx.x];
#pragma unroll
  for (int j = 0; j < 4; ++j) {
    int idx = base + j;
    if (idx < n) { off[idx] = run; cur[idx] = run; }
    run += v[j];
  }
  if (b == 0 && threadIdx.x == 0) {
    int tot = 0;
    for (int j = 0; j < nblk; ++j) tot += bsum[j];
    off[n] = tot;
  }
}

__global__ __launch_bounds__(256) void seg_fill_k(const int* __restrict__ idx,
    int* __restrict__ cur, int* __restrict__ ids, int n) {
  int t = blockIdx.x * 256 + threadIdx.x;
  if (t < n) { int p = atomicAdd(&cur[idx[t]], 1); ids[p] = t; }
}

// ---------------- gather aggregations ----------------

__global__ __launch_bounds__(256) void gine_agg_k(const int* __restrict__ off,
    const int* __restrict__ ids, const int* __restrict__ ei, const int* __restrict__ ef,
    const float* __restrict__ bemb, const float* __restrict__ x,
    float* __restrict__ out, int N) {
  int n = blockIdx.x * 8 + (threadIdx.x >> 5);
  if (n >= N) return;
  int c4 = (threadIdx.x & 31) * 4;
  float4 acc = *(const float4*)(x + (size_t)n * H + c4);
  float4 acc2 = make_float4(0.f, 0.f, 0.f, 0.f);
  int p0 = off[n], p1 = off[n + 1];
  int p = p0;
  for (; p + 1 < p1; p += 2) {
    int e0 = ids[p], e1 = ids[p + 1];
    int s0 = ei[e0], s1 = ei[e1];
    const int* f0 = ef + (size_t)e0 * 3;
    const int* f1 = ef + (size_t)e1 * 3;
    float4 a0 = *(const float4*)(bemb + (size_t)f0[0] * H + c4);
    float4 a1 = *(const float4*)(bemb + ((size_t)100 + f0[1]) * H + c4);
    float4 a2 = *(const float4*)(bemb + ((size_t)200 + f0[2]) * H + c4);
    float4 xa = *(const float4*)(x + (size_t)s0 * H + c4);
    float4 b0 = *(const float4*)(bemb + (size_t)f1[0] * H + c4);
    float4 b1 = *(const float4*)(bemb + ((size_t)100 + f1[1]) * H + c4);
    float4 b2 = *(const float4*)(bemb + ((size_t)200 + f1[2]) * H + c4);
    float4 xb = *(const float4*)(x + (size_t)s1 * H + c4);
    acc.x += fmaxf(xa.x + a0.x + a1.x + a2.x, 0.f);
    acc.y += fmaxf(xa.y + a0.y + a1.y + a2.y, 0.f);
    acc.z += fmaxf(xa.z + a0.z + a1.z + a2.z, 0.f);
    acc.w += fmaxf(xa.w + a0.w + a1.w + a2.w, 0.f);
    acc2.x += fmaxf(xb.x + b0.x + b1.x + b2.x, 0.f);
    acc2.y += fmaxf(xb.y + b0.y + b1.y + b2.y, 0.f);
    acc2.z += fmaxf(xb.z + b0.z + b1.z + b2.z, 0.f);
    acc2.w += fmaxf(xb.w + b0.w + b1.w + b2.w, 0.f);
  }
  if (p < p1) {
    int e = ids[p];
    int src = ei[e];
    const int* f = ef + (size_t)e * 3;
    float4 v0 = *(const float4*)(bemb + (size_t)f[0] * H + c4);
    float4 v1 = *(const float4*)(bemb + ((size_t)100 + f[1]) * H + c4);
    float4 v2 = *(const float4*)(bemb + ((size_t)200 + f[2]) * H + c4);
    float4 xs = *(const float4*)(x + (size_t)src * H + c4);
    acc.x += fmaxf(xs.x + v0.x + v1.x + v2.x, 0.f);
    acc.y += fmaxf(xs.y + v0.y + v1.y + v2.y, 0.f);
    acc.z += fmaxf(xs.z + v0.z + v1.z + v2.z, 0.f);
    acc.w += fmaxf(xs.w + v0.w + v1.w + v2.w, 0.f);
  }
  acc.x += acc2.x; acc.y += acc2.y; acc.z += acc2.z; acc.w += acc2.w;
  *(float4*)(out + (size_t)n * H + c4) = acc;
}

__global__ __launch_bounds__(256) void gather_agg_k(const int* __restrict__ off,
    const int* __restrict__ ids, const int* __restrict__ sidx,
    const float* __restrict__ src, const float* __restrict__ base,
    float* __restrict__ out, int N) {
  int n = blockIdx.x * 8 + (threadIdx.x >> 5);
  if (n >= N) return;
  int c4 = (threadIdx.x & 31) * 4;
  float4 acc = make_float4(0.f, 0.f, 0.f, 0.f);
  float4 acc2 = make_float4(0.f, 0.f, 0.f, 0.f);
  if (base) acc = *(const float4*)(base + (size_t)n * H + c4);
  int p0 = off[n], p1 = off[n + 1];
  int p = p0;
  for (; p + 1 < p1; p += 2) {
    int m0 = ids[p], m1 = ids[p + 1];
    int s0 = sidx ? sidx[m0] : m0;
    int s1 = sidx ? sidx[m1] : m1;
    float4 v0 = *(const float4*)(src + (size_t)s0 * H + c4);
    float4 v1 = *(const float4*)(src + (size_t)s1 * H + c4);
    acc.x += v0.x; acc.y += v0.y; acc.z += v0.z; acc.w += v0.w;
    acc2.x += v1.x; acc2.y += v1.y; acc2.z += v1.z; acc2.w += v1.w;
  }
  if (p < p1) {
    int m = ids[p];
    int sr = sidx ? sidx[m] : m;
    float4 v = *(const float4*)(src + (size_t)sr * H + c4);
    acc.x += v.x; acc.y += v.y; acc.z += v.z; acc.w += v.w;
  }
  acc.x += acc2.x; acc.y += acc2.y; acc.z += acc2.z; acc.w += acc2.w;
  *(float4*)(out + (size_t)n * H + c4) = acc;
}

__device__ __forceinline__ int lowb(const int* __restrict__ a, int n, int v) {
  int lo = 0, hi = n;
  while (lo < hi) { int mid = (lo + hi) >> 1; if (a[mid] < v) lo = mid + 1; else hi = mid; }
  return lo;
}

__global__ __launch_bounds__(256) void pool_mean_k(const int* __restrict__ bidx,
    const float* __restrict__ src, float* __restrict__ out, int n, int G) {
  int g = blockIdx.x * 8 + (threadIdx.x >> 5);
  if (g >= G) return;
  int c4 = (threadIdx.x & 31) * 4;
  int lo = lowb(bidx, n, g), hi = lowb(bidx, n, g + 1);
  float4 acc = make_float4(0.f, 0.f, 0.f, 0.f);
  for (int r = lo; r < hi; ++r) {
    float4 v = *(const float4*)(src + (size_t)r * H + c4);
    acc.x += v.x; acc.y += v.y; acc.z += v.z; acc.w += v.w;
  }
  float inv = 1.0f / (float)max(hi - lo, 1);
  acc.x *= inv; acc.y *= inv; acc.z *= inv; acc.w *= inv;
  *(float4*)(out + (size_t)g * H + c4) = acc;
}

// ---------------- batchnorm helpers ----------------

__global__ void bn_final_k(float* __restrict__ ssum, float* __restrict__ ssq,
    float* __restrict__ mu, float* __restrict__ rsig, int C, float invM) {
  int c = threadIdx.x;
  if (c < C) {
    float m = ssum[c] * invM;
    float v = ssq[c] * invM - m * m;
    mu[c] = m;
    rsig[c] = rsqrtf(v + 1e-5f);
  }
  ssum[c] = 0.f;
  ssq[c] = 0.f;
}

__global__ __launch_bounds__(256) void bn_apply_relu_k(const float* __restrict__ X,
    const float* __restrict__ mu, const float* __restrict__ rsig,
    float* __restrict__ Out, int M) {
  long long t = (long long)blockIdx.x * 256 + threadIdx.x;
  if (t >= (long long)M * 32) return;
  int c4 = ((int)(t & 31)) * 4;
  float4 v = ((const float4*)X)[t];
  float4 m4 = *(const float4*)&mu[c4];
  float4 r4 = *(const float4*)&rsig[c4];
  v.x = fmaxf((v.x - m4.x) * r4.x, 0.f);
  v.y = fmaxf((v.y - m4.y) * r4.y, 0.f);
  v.z = fmaxf((v.z - m4.z) * r4.z, 0.f);
  v.w = fmaxf((v.w - m4.w) * r4.w, 0.f);
  ((float4*)Out)[t] = v;
}

// ---------------- MFMA MLP stats: pair-tiled 512-thread blocks ----------------

__global__ __launch_bounds__(512) void mlp_stats_mfma_k(
    const float* __restrict__ A, const short* __restrict__ w1h, const short* __restrict__ w1l,
    float* __restrict__ ssum, float* __restrict__ ssq, int M, int npairs) {
  __shared__ __align__(16) short Wch[8192], Wcl[8192];
  __shared__ float sRed[256], qRed[256];
  int tid = threadIdx.x;
  if (tid < 256) { sRed[tid] = 0.f; qRed[tid] = 0.f; }
  int w = tid >> 6, l = tid & 63, l15 = l & 15, lg = l >> 4;
  int h = w >> 2, wl = w & 3;
  float sAcc[16], qAcc[16];
#pragma unroll
  for (int nt = 0; nt < 16; ++nt) { sAcc[nt] = 0.f; qAcc[nt] = 0.f; }
  for (int pb = blockIdx.x; pb < npairs; pb += gridDim.x) {
    int tile = pb * 2 + h;
    int arow = tile * 64 + wl * 16 + l15;
    bool av = arow < M;
    bf8 ah[4], al_[4];
    load_afrags(A + (size_t)arow * 128 + lg * 8, av, 1.f, ah, al_);
    for (int ch = 0; ch < 4; ++ch) {
      __syncthreads();
      const bf8* srcH = (const bf8*)(w1h + ch * 8192);
      const bf8* srcL = (const bf8*)(w1l + ch * 8192);
      for (int it = tid; it < 1024; it += 512) {
        stage16(srcH + it, ((bf8*)Wch) + it);
        stage16(srcL + it, ((bf8*)Wcl) + it);
      }
      __syncthreads();
#pragma unroll
      for (int ntl = 0; ntl < 4; ++ntl) {
        f32x4v c = {0.f, 0.f, 0.f, 0.f};
#pragma unroll
        for (int ks = 0; ks < 4; ++ks) {
          bf8 bh = *(const bf8*)&Wch[(ntl * 4 + ks) * 512 + l * 8];
          bf8 bl = *(const bf8*)&Wcl[(ntl * 4 + ks) * 512 + l * 8];
          c = mfma16(al_[ks], bh, c);
          c = mfma16(ah[ks], bl, c);
          c = mfma16(ah[ks], bh, c);
        }
        int nt = ch * 4 + ntl;
        if (av) {
          sAcc[nt] += c[0] + c[1] + c[2] + c[3];
          qAcc[nt] += c[0]*c[0] + c[1]*c[1] + c[2]*c[2] + c[3]*c[3];
        }
      }
    }
  }
  __syncthreads();
#pragma unroll
  for (int nt = 0; nt < 16; ++nt) {
    float s = sAcc[nt], q = qAcc[nt];
    s += __shfl_xor(s, 16); s += __shfl_xor(s, 32);
    q += __shfl_xor(q, 16); q += __shfl_xor(q, 32);
    if (l < 16) { atomicAdd(&sRed[nt * 16 + l], s); atomicAdd(&qRed[nt * 16 + l], q); }
  }
  __syncthreads();
  if (tid < 256) { atomicAdd(&ssum[tid], sRed[tid]); atomicAdd(&ssq[tid], qRed[tid]); }
}

// ---------------- MFMA fused MLP: pair-tiled, double-buffered W prefetch ----------------
// 8 phases/tile: barrier; stage(chunk c+1 -> other buf); MFMA(chunk c).
// h1f is wave-local (same-wave rows for write and a2-read) -> no barrier needed for it.

__global__ __launch_bounds__(512) void mlp_fused_mfma_k(
    float* __restrict__ A, const short* __restrict__ w1h, const short* __restrict__ w1l,
    const short* __restrict__ w2h, const short* __restrict__ w2l,
    const float* __restrict__ mu, const float* __restrict__ rsig,
    float* __restrict__ ssum, float* __restrict__ ssq, int M, int npairs) {
  __shared__ __align__(16) short Wch[2][8192], Wcl[2][8192];  // 64 KB
  __shared__ __align__(16) float h1f[2][64][132];             // 67.6 KB
  __shared__ float sRed[128], qRed[128];
  int tid = threadIdx.x;
  if (tid < 128) { sRed[tid] = 0.f; qRed[tid] = 0.f; }
  int w = tid >> 6, l = tid & 63, l15 = l & 15, lg = l >> 4;
  int h = w >> 2, wl = w & 3;
  float sAcc[8], qAcc[8];
#pragma unroll
  for (int nt = 0; nt < 8; ++nt) { sAcc[nt] = 0.f; qAcc[nt] = 0.f; }
  for (int pb = blockIdx.x; pb < npairs; pb += gridDim.x) {
    int tile = pb * 2 + h;
    int arow = tile * 64 + wl * 16 + l15;
    bool av = arow < M;
    f32x4v acc[8];
#pragma unroll
    for (int nt = 0; nt < 8; ++nt) acc[nt] = (f32x4v){0.f, 0.f, 0.f, 0.f};
    bf8 ah[4], al_[4];
    load_afrags(A + (size_t)arow * 128 + lg * 8, av, 1.f, ah, al_);
    bf8 a2h[4], a2l[4];

    auto stageW1 = [&](int cbase, int buf) {
      const bf8* srcH = (const bf8*)(w1h + cbase * 2048);
      const bf8* srcL = (const bf8*)(w1l + cbase * 2048);
      for (int it = tid; it < 1024; it += 512) {
        stage16(srcH + it, ((bf8*)Wch[buf]) + it);
        stage16(srcL + it, ((bf8*)Wcl[buf]) + it);
      }
    };
    auto stageW2 = [&](int kh, int c2, int buf) {
      for (int it = tid; it < 1024; it += 512) {
        int e = it * 8;
        int ntl = e >> 11, rem = e & 2047;
        int ks2 = rem >> 9, s = rem & 511;
        int src = ((c2 * 4 + ntl) * 8 + kh * 4 + ks2) * 512 + s;
        stage16((const bf8*)(w2h + src), ((bf8*)Wch[buf]) + it);
        stage16((const bf8*)(w2l + src), ((bf8*)Wcl[buf]) + it);
      }
    };
    auto mfmaW1 = [&](int cbase, int buf) {
#pragma unroll
      for (int ntl = 0; ntl < 4; ++ntl) {
        f32x4v c = {0.f, 0.f, 0.f, 0.f};
#pragma unroll
        for (int ks = 0; ks < 4; ++ks) {
          bf8 bh = *(const bf8*)&Wch[buf][(ntl * 4 + ks) * 512 + l * 8];
          bf8 bl = *(const bf8*)&Wcl[buf][(ntl * 4 + ks) * 512 + l * 8];
          c = mfma16(al_[ks], bh, c);
          c = mfma16(ah[ks], bl, c);
          c = mfma16(ah[ks], bh, c);
        }
        int cn = cbase + ntl;
        int cc = cn * 16 + l15;
        float mm = mu[cc], rs = rsig[cc];
#pragma unroll
        for (int r = 0; r < 4; ++r) {
          float t = fmaxf((c[r] - mm) * rs, 0.f);
          h1f[h][wl * 16 + lg * 4 + r][(cn & 7) * 16 + l15] = t;
        }
      }
    };
    auto buildA2 = [&]() {
#pragma unroll
      for (int ks2 = 0; ks2 < 4; ++ks2) {
        const float* hp = &h1f[h][wl * 16 + l15][ks2 * 32 + lg * 8];
#pragma unroll
        for (int j = 0; j < 8; ++j) {
          short hh, ll; splitf(hp[j], hh, ll);
          a2h[ks2][j] = hh; a2l[ks2][j] = ll;
        }
      }
    };
    auto mfmaW2 = [&](int c2, int buf) {
#pragma unroll
      for (int ntl = 0; ntl < 4; ++ntl) {
        f32x4v c = acc[c2 * 4 + ntl];
#pragma unroll
        for (int ks2 = 0; ks2 < 4; ++ks2) {
          bf8 bh = *(const bf8*)&Wch[buf][(ntl * 4 + ks2) * 512 + l * 8];
          bf8 bl = *(const bf8*)&Wcl[buf][(ntl * 4 + ks2) * 512 + l * 8];
          c = mfma16(a2l[ks2], bh, c);
          c = mfma16(a2h[ks2], bl, c);
          c = mfma16(a2h[ks2], bh, c);
        }
        acc[c2 * 4 + ntl] = c;
      }
    };

    __syncthreads();            // prior tile's buffer reads complete
    stageW1(0, 0);              // chunk 0 (exposed once per tile)
    // P0
    __syncthreads();
    stageW1(4, 1);
    mfmaW1(0, 0);
    // P1
    __syncthreads();
    stageW2(0, 0, 0);
    mfmaW1(4, 1);
    buildA2();                  // kh0 a2 frags (wave-local h1f)
    // P2
    __syncthreads();
    stageW2(0, 1, 1);
    mfmaW2(0, 0);
    // P3
    __syncthreads();
    stageW1(8, 0);
    mfmaW2(1, 1);
    // P4
    __syncthreads();
    stageW1(12, 1);
    mfmaW1(8, 0);
    // P5
    __syncthreads();
    stageW2(1, 0, 0);
    mfmaW1(12, 1);
    buildA2();                  // kh1 a2 frags
    // P6
    __syncthreads();
    stageW2(1, 1, 1);
    mfmaW2(0, 0);
    // P7
    __syncthreads();
    mfmaW2(1, 1);

    int base = tile * 64 + wl * 16;
#pragma unroll
    for (int nt = 0; nt < 8; ++nt) {
      int cc = nt * 16 + l15;
#pragma unroll
      for (int r = 0; r < 4; ++r) {
        int gr = base + lg * 4 + r;
        if (gr < M) {
          float vv = acc[nt][r];
          A[(size_t)gr * 128 + cc] = vv;
          sAcc[nt] += vv;
          qAcc[nt] = fmaf(vv, vv, qAcc[nt]);
        }
      }
    }
  }
  __syncthreads();
#pragma unroll
  for (int nt = 0; nt < 8; ++nt) {
    float s = sAcc[nt], q = qAcc[nt];
    s += __shfl_xor(s, 16); s += __shfl_xor(s, 32);
    q += __shfl_xor(q, 16); q += __shfl_xor(q, 32);
    if (l < 16) { atomicAdd(&sRed[nt * 16 + l], s); atomicAdd(&qRed[nt * 16 + l], q); }
  }
  __syncthreads();
  if (tid < 128) { atomicAdd(&ssum[tid], sRed[tid]); atomicAdd(&ssq[tid], qRed[tid]); }
}

// ---------------- MFMA 128x128 GEMM: Out = Out + relu((A*aux) @ W) ----------------
// hi-plane staged in LDS (32 KB); lo-plane read directly from L2-resident global.

__global__ __launch_bounds__(256) void gemm128_mfma_k(
    const float* __restrict__ A0, const float* __restrict__ AUX,
    const short* __restrict__ wh, const short* __restrict__ wl,
    float* __restrict__ Out, int M, int ntiles) {
  __shared__ __align__(16) short Wh[16384];
  int tid = threadIdx.x;
  for (int i = tid; i < 2048; i += 256) {
    stage16((const f32x4v*)wh + i, ((f32x4v*)Wh) + i);
  }
  __syncthreads();
  int w = tid >> 6, l = tid & 63, l15 = l & 15, lg = l >> 4;
  const bf8* wlp = (const bf8*)wl;
  for (int tb = blockIdx.x; tb < ntiles; tb += gridDim.x) {
    int arow = tb * 64 + w * 16 + l15;
    bool av = arow < M;
    float sc = av ? AUX[arow] : 0.f;
    bf8 ah[4], al_[4];
    load_afrags(A0 + (size_t)arow * 128 + lg * 8, av, sc, ah, al_);
    int base = tb * 64 + w * 16;
#pragma unroll 2
    for (int nt = 0; nt < 8; ++nt) {
      f32x4v c = {0.f, 0.f, 0.f, 0.f};
#pragma unroll
      for (int ks = 0; ks < 4; ++ks) {
        bf8 bh = *(const bf8*)&Wh[(nt * 4 + ks) * 512 + l * 8];
        bf8 bl = wlp[(nt * 4 + ks) * 64 + l];
        c = mfma16(al_[ks], bh, c);
        c = mfma16(ah[ks], bl, c);
        c = mfma16(ah[ks], bh, c);
      }
#pragma unroll
      for (int r = 0; r < 4; ++r) {
        int gr = base + lg * 4 + r;
        if (gr < M) {
          size_t o = (size_t)gr * 128 + nt * 16 + l15;
          Out[o] = Out[o] + fmaxf(c[r], 0.f);
        }
      }
    }
  }
}

// ---------------- f32 GEMM for readout ----------------
template<int EPI>
__global__ __launch_bounds__(256) void gemm_k(
    const float* __restrict__ A0, const float* __restrict__ W,
    float* __restrict__ Out, int M) {
  __shared__ __align__(16) float Ash[64][64];
  int tid = threadIdx.x;
  int tc = tid & 63, tr = tid >> 6;
  int row0 = blockIdx.x * 64;
  float acc[16][2];
#pragma unroll
  for (int i = 0; i < 16; ++i) { acc[i][0] = 0.f; acc[i][1] = 0.f; }
  for (int k0 = 0; k0 < 128; k0 += 64) {
#pragma unroll
    for (int it = 0; it < 4; ++it) {
      int fidx = tid + it * 256;
      int r = fidx >> 4, c4 = (fidx & 15) << 2;
      int gr = row0 + r;
      float4 v = make_float4(0.f, 0.f, 0.f, 0.f);
      if (gr < M) v = *(const float4*)(A0 + (size_t)gr * 128 + k0 + c4);
      *(float4*)&Ash[r][c4] = v;
    }
    __syncthreads();
    const float* Wp = W + (size_t)k0 * 128 + tc;
    for (int kk = 0; kk < 64; kk += 4) {
      float w[4][2];
#pragma unroll
      for (int kj = 0; kj < 4; ++kj)
#pragma unroll
        for (int j = 0; j < 2; ++j) w[kj][j] = Wp[(size_t)(kk + kj) * 128 + j * 64];
#pragma unroll
      for (int i = 0; i < 16; ++i) {
        float4 a = *(const float4*)&Ash[tr * 16 + i][kk];
#pragma unroll
        for (int j = 0; j < 2; ++j) {
          acc[i][j] = fmaf(a.x, w[0][j], acc[i][j]);
          acc[i][j] = fmaf(a.y, w[1][j], acc[i][j]);
          acc[i][j] = fmaf(a.z, w[2][j], acc[i][j]);
          acc[i][j] = fmaf(a.w, w[3][j], acc[i][j]);
        }
      }
    }
    __syncthreads();
  }
#pragma unroll
  for (int i = 0; i < 16; ++i) {
    int gr = row0 + tr * 16 + i;
    if (gr < M) {
#pragma unroll
      for (int j = 0; j < 2; ++j) {
        size_t o = (size_t)gr * 128 + tc + j * 64;
        float v = acc[i][j];
        if (EPI == 0) Out[o] = v;
        else Out[o] = fmaxf(Out[o] + v, 0.f);
      }
    }
  }
}

// ---------------- host ----------------

static inline int cdivll(long long a, long long b) { return (int)((a + b - 1) / b); }

extern "C" void kernel_launch(void* const* d_in, const int* in_sizes, int n_in,
                              void* d_out, int out_size, void* d_ws, size_t ws_size,
                              hipStream_t stream) {
  const int* node_feat  = (const int*)d_in[0];
  const int* edge_index = (const int*)d_in[1];
  const int* edge_feat  = (const int*)d_in[2];
  const int* batch      = (const int*)d_in[3];
  const int* map_row    = (const int*)d_in[4];
  const int* map_col    = (const int*)d_in[5];
  const int* rg_ei      = (const int*)d_in[6];
  const int* rg_feat    = (const int*)d_in[7];
  const int* tree_batch = (const int*)d_in[8];
  const float* atom_emb   = (const float*)d_in[10];
  const float* bond_emb   = (const float*)d_in[11];
  const float* rg_emb     = (const float*)d_in[12];
  const float* atom_W1    = (const float*)d_in[13];
  const float* atom_W2    = (const float*)d_in[14];
  const float* rg_W1      = (const float*)d_in[15];
  const float* rg_W2      = (const float*)d_in[16];
  const float* raw2rg_W   = (const float*)d_in[17];
  const float* rg2raw_W   = (const float*)d_in[18];
  const float* atom_lin_W = (const float*)d_in[19];
  const float* rg_lin_W   = (const float*)d_in[20];
  const float* lin_W      = (const float*)d_in[21];

  const int N   = in_sizes[0] / 9;
  const int E   = in_sizes[1] / 2;
  const int M   = in_sizes[4];
  const int NRG = in_sizes[7];
  const int ERG = in_sizes[6] / 2;
  const int G   = out_size / H;
  if (N <= 0 || G <= 0) return;

  const size_t NH = (size_t)N * H, RH = (size_t)NRG * H, GH = (size_t)G * H;
  const int cmax = max(N, NRG);

  const size_t nfloat = 2 * NH + RH + (size_t)NRG + (size_t)N + 2048;
  const size_t nint = (size_t)(N + 1) * 2 + (size_t)(NRG + 1) * 2
                    + (size_t)E + 2 * (size_t)M + (size_t)ERG + (size_t)cmax + 1024;
  const size_t nshort = 3 * (4 * 32768 + 2 * 16384);
  const size_t need = nfloat * 4 + nint * 4 + nshort * 2 + 256;
  if (ws_size < need) return;

  float* ws = (float*)d_ws;
  size_t off = 0;
  auto alloc = [&](size_t n) { float* p = ws + off; off += n; return p; };
  float* x       = alloc(NH);
  float* abuf    = alloc(NH);
  float* rg      = alloc(RH);
  float* inv_col = alloc((size_t)NRG);
  float* inv_row = alloc((size_t)N);
  float* ssum = alloc(256);
  float* ssq  = alloc(256);
  float* mu   = alloc(256);
  float* rsig = alloc(256);

  int* ip = (int*)(ws + off);
  size_t ioff = 0;
  auto ialloc = [&](size_t n) { int* p = ip + ioff; ioff += n; return p; };
  int* off_dst = ialloc((size_t)N + 1);
  int* off_col = ialloc((size_t)NRG + 1);
  int* off_row = ialloc((size_t)N + 1);
  int* off_rg  = ialloc((size_t)NRG + 1);
  int* ids_dst = ialloc((size_t)E);
  int* ids_col = ialloc((size_t)M);
  int* ids_row = ialloc((size_t)M);
  int* ids_rg  = ialloc((size_t)ERG);
  int* tmp_cnt = ialloc((size_t)cmax);
  int* bsum    = ialloc(1024);

  short* sp = (short*)(ip + ioff);
  size_t soff = 0;
  auto salloc = [&](size_t n) { short* p = sp + soff; soff += n; return p; };
  short* paW1h = salloc(3 * 32768); short* paW1l = salloc(3 * 32768);
  short* paW2h = salloc(3 * 32768); short* paW2l = salloc(3 * 32768);
  short* prW1h = salloc(3 * 32768); short* prW1l = salloc(3 * 32768);
  short* prW2h = salloc(3 * 32768); short* prW2l = salloc(3 * 32768);
  short* p2gh  = salloc(3 * 16384); short* p2gl  = salloc(3 * 16384);
  short* pg2h  = salloc(3 * 16384); short* pg2l  = salloc(3 * 16384);

  const int ta = (N + 63) >> 6, trg = (NRG + 63) >> 6;
  const int pa = (ta + 1) >> 1, prg = (trg + 1) >> 1;
  const int ga2 = pa < 512 ? pa : 512, grg2 = prg < 512 ? prg : 512;
  const int ga = ta < 1024 ? ta : 1024, grg = trg < 1024 ? trg : 1024;

  // ---- pack weights ----
  pack_w_k<<<dim3(128, 3), 256, 0, stream>>>(atom_W1, paW1h, paW1l, 128, 256);
  pack_w_k<<<dim3(128, 3), 256, 0, stream>>>(atom_W2, paW2h, paW2l, 256, 128);
  pack_w_k<<<dim3(128, 3), 256, 0, stream>>>(rg_W1, prW1h, prW1l, 128, 256);
  pack_w_k<<<dim3(128, 3), 256, 0, stream>>>(rg_W2, prW2h, prW2l, 256, 128);
  pack_w_k<<<dim3(64, 3), 256, 0, stream>>>(raw2rg_W, p2gh, p2gl, 128, 128);
  pack_w_k<<<dim3(64, 3), 256, 0, stream>>>(rg2raw_W, pg2h, pg2l, 128, 128);

  // ---- CSR builds ----
  auto build_csr = [&](const int* idx, int nelem, int nrows, int* offs, int* ids,
                       float* inv) {
    hipMemsetAsync(tmp_cnt, 0, (size_t)nrows * 4, stream);
    icount_k<<<cdivll(nelem, 256), 256, 0, stream>>>(idx, tmp_cnt, nelem);
    if (inv) inv_from_int_k<<<cdivll(nrows, 256), 256, 0, stream>>>(tmp_cnt, inv, nrows);
    int nblk = cdivll(nrows, 1024);
    seg_blocksum_k<<<nblk, 256, 0, stream>>>(tmp_cnt, bsum, nrows);
    seg_scan_k<<<nblk, 256, 0, stream>>>(tmp_cnt, bsum, offs, tmp_cnt, nrows, nblk);
    seg_fill_k<<<cdivll(nelem, 256), 256, 0, stream>>>(idx, tmp_cnt, ids, nelem);
  };
  build_csr(edge_index + E, E, N, off_dst, ids_dst, nullptr);
  build_csr(map_col, M, NRG, off_col, ids_col, inv_col);
  build_csr(map_row, M, N, off_row, ids_row, inv_row);
  build_csr(rg_ei + ERG, ERG, NRG, off_rg, ids_rg, nullptr);

  // ---- encoders; initial stats zero ----
  hipMemsetAsync(ssum, 0, 512 * 4, stream);
  atom_encode_k<<<cdivll(NH, 256), 256, 0, stream>>>(node_feat, atom_emb, x, N);
  rg_init_k<<<cdivll(RH, 256), 256, 0, stream>>>(rg_feat, rg_emb, rg, NRG);

  for (int i = 0; i < 3; ++i) {
    // --- GINE: abuf = x + sum relu(x[src]+e) ---
    gine_agg_k<<<cdivll(N, 8), 256, 0, stream>>>(off_dst, ids_dst, edge_index, edge_feat,
        bond_emb + (size_t)i * 3 * 100 * H, x, abuf, N);
    // --- atom MLP ---
    mlp_stats_mfma_k<<<ga2, 512, 0, stream>>>(abuf, paW1h + i * 32768, paW1l + i * 32768, ssum, ssq, N, pa);
    bn_final_k<<<1, 256, 0, stream>>>(ssum, ssq, mu, rsig, 256, 1.0f / N);
    mlp_fused_mfma_k<<<ga2, 512, 0, stream>>>(abuf, paW1h + i * 32768, paW1l + i * 32768,
        paW2h + i * 32768, paW2l + i * 32768, mu, rsig, ssum, ssq, N, pa);
    bn_final_k<<<1, 256, 0, stream>>>(ssum, ssq, mu, rsig, 128, 1.0f / N);
    bn_apply_relu_k<<<cdivll((long long)N * 32, 256), 256, 0, stream>>>(abuf, mu, rsig, x, N);

    // --- raw -> rg ---
    gather_agg_k<<<cdivll(NRG, 8), 256, 0, stream>>>(off_col, ids_col, map_row, x, nullptr, abuf, NRG);
    gemm128_mfma_k<<<grg, 256, 0, stream>>>(abuf, inv_col, p2gh + i * 16384, p2gl + i * 16384,
        rg, NRG, trg);

    // --- rg GIN ---
    gather_agg_k<<<cdivll(NRG, 8), 256, 0, stream>>>(off_rg, ids_rg, rg_ei, rg, rg, abuf, NRG);
    mlp_stats_mfma_k<<<grg2, 512, 0, stream>>>(abuf, prW1h + i * 32768, prW1l + i * 32768, ssum, ssq, NRG, prg);
    bn_final_k<<<1, 256, 0, stream>>>(ssum, ssq, mu, rsig, 256, 1.0f / NRG);
    mlp_fused_mfma_k<<<grg2, 512, 0, stream>>>(abuf, prW1h + i * 32768, prW1l + i * 32768,
        prW2h + i * 32768, prW2l + i * 32768, mu, rsig, ssum, ssq, NRG, prg);
    bn_final_k<<<1, 256, 0, stream>>>(ssum, ssq, mu, rsig, 128, 1.0f / NRG);
    bn_apply_relu_k<<<cdivll((long long)NRG * 32, 256), 256, 0, stream>>>(abuf, mu, rsig, rg, NRG);

    // --- rg -> raw ---
    gather_agg_k<<<cdivll(N, 8), 256, 0, stream>>>(off_row, ids_row, map_col, rg, nullptr, abuf, N);
    gemm128_mfma_k<<<ga, 256, 0, stream>>>(abuf, inv_row, pg2h + i * 16384, pg2l + i * 16384,
        x, N, ta);
  }

  // ---- readout ----
  float* xg  = abuf;
  float* rgg = abuf + GH;
  float* P   = abuf + 2 * GH;
  pool_mean_k<<<cdivll(G, 8), 256, 0, stream>>>(batch, x, xg, N, G);
  pool_mean_k<<<cdivll(G, 8), 256, 0, stream>>>(tree_batch, rg, rgg, NRG, G);
  gemm_k<0><<<cdivll(G, 64), 256, 0, stream>>>(xg, atom_lin_W, P, G);
  gemm_k<2><<<cdivll(G, 64), 256, 0, stream>>>(rgg, rg_lin_W, P, G);
  gemm_k<0><<<cdivll(G, 64), 256, 0, stream>>>(P, lin_W, (float*)d_out, G);
}